// Round 3
// baseline (33.200 us; speedup 1.0000x reference)
//
#include <hip/hip_runtime.h>
#include <math.h>

#define NODES   100000
#define DIM     128
#define NEDGES  1600000   // 4 * 400000

#define LOG2E 1.44269504088896340736f

// clang-native vector types (accepted by __builtin_nontemporal_*; HIP_vector_type is not)
typedef int   v4i __attribute__((ext_vector_type(4)));
typedef float v4f __attribute__((ext_vector_type(4)));

// Phase 1: per-node projections pu[n] = dot(h[n], Wu), pv[n] = dot(h[n], Wv) + bias.
// 32 lanes cooperate per node; each lane loads one float4 (16B). A 64-lane wave
// covers 2 consecutive nodes = 1024 contiguous bytes -> fully coalesced.
__global__ __launch_bounds__(256) void node_proj_kernel(
    const float* __restrict__ h,
    const float* __restrict__ W,      // 256 floats: Wu = W[0:128], Wv = W[128:256]
    const float* __restrict__ bias_ptr,
    float* __restrict__ pu,
    float* __restrict__ pv,
    int n_nodes)
{
    int tid  = blockIdx.x * blockDim.x + threadIdx.x;
    int lane = tid & 31;
    int node = tid >> 5;
    if (node >= n_nodes) return;

    const v4f hv = __builtin_nontemporal_load(
        reinterpret_cast<const v4f*>(h + (size_t)node * DIM + lane * 4));
    const v4f wu = *reinterpret_cast<const v4f*>(W + lane * 4);
    const v4f wv = *reinterpret_cast<const v4f*>(W + DIM + lane * 4);

    float su = hv.x * wu.x + hv.y * wu.y + hv.z * wu.z + hv.w * wu.w;
    float sv = hv.x * wv.x + hv.y * wv.y + hv.z * wv.z + hv.w * wv.w;

    // Butterfly reduce across the 32-lane group (xor masks <= 16 stay in-group).
    #pragma unroll
    for (int off = 16; off >= 1; off >>= 1) {
        su += __shfl_xor(su, off);
        sv += __shfl_xor(sv, off);
    }

    if (lane == 0) {
        pu[node] = su;
        pv[node] = sv + bias_ptr[0];   // fold bias once per node
    }
}

// Phase 2: per-edge score. 4 edges per thread, vectorized index/output IO.
// pu/pv (800 KB total) are L2/L3-resident, so the 2 gathers per edge are cheap.
// Streaming src/dst/out use nontemporal hints to avoid evicting the tables.
__global__ __launch_bounds__(256) void edge_score_kernel(
    const int*   __restrict__ src,
    const int*   __restrict__ dst,
    const float* __restrict__ pu,
    const float* __restrict__ pv,
    float* __restrict__ out,
    int n_quads)
{
    int i = blockIdx.x * blockDim.x + threadIdx.x;
    if (i >= n_quads) return;

    v4i s4 = __builtin_nontemporal_load(reinterpret_cast<const v4i*>(src) + i);
    v4i d4 = __builtin_nontemporal_load(reinterpret_cast<const v4i*>(dst) + i);

    // Issue all 8 gathers up-front so their latencies overlap.
    float a0 = pu[s4.x], b0 = pv[d4.x];
    float a1 = pu[s4.y], b1 = pv[d4.y];
    float a2 = pu[s4.z], b2 = pv[d4.z];
    float a3 = pu[s4.w], b3 = pv[d4.w];

    v4f r;
    r.x = a0 + b0;
    r.y = a1 + b1;
    r.z = a2 + b2;
    r.w = a3 + b3;

    // sigmoid(x) = 1 / (1 + 2^(-x*log2e)) via HW exp2 + rcp (~1 ulp each).
    r.x = __builtin_amdgcn_rcpf(1.0f + __builtin_amdgcn_exp2f(-r.x * LOG2E));
    r.y = __builtin_amdgcn_rcpf(1.0f + __builtin_amdgcn_exp2f(-r.y * LOG2E));
    r.z = __builtin_amdgcn_rcpf(1.0f + __builtin_amdgcn_exp2f(-r.z * LOG2E));
    r.w = __builtin_amdgcn_rcpf(1.0f + __builtin_amdgcn_exp2f(-r.w * LOG2E));

    __builtin_nontemporal_store(r, reinterpret_cast<v4f*>(out) + i);
}

extern "C" void kernel_launch(void* const* d_in, const int* in_sizes, int n_in,
                              void* d_out, int out_size, void* d_ws, size_t ws_size,
                              hipStream_t stream) {
    const float* h    = (const float*)d_in[0];
    const int*   src  = (const int*)d_in[1];
    const int*   dst  = (const int*)d_in[2];
    const float* W    = (const float*)d_in[3];   // (1, 256)
    const float* bias = (const float*)d_in[4];   // (1,)
    float* out = (float*)d_out;

    float* pu = (float*)d_ws;                    // NODES floats
    float* pv = pu + NODES;                      // NODES floats

    // Phase 1: 32 lanes/node -> NODES*32 threads.
    {
        int threads = 256;
        int total   = NODES * 32;
        int blocks  = (total + threads - 1) / threads;
        node_proj_kernel<<<blocks, threads, 0, stream>>>(h, W, bias, pu, pv, NODES);
    }

    // Phase 2: 4 edges/thread.
    {
        int threads = 256;
        int n_quads = NEDGES / 4;
        int blocks  = (n_quads + threads - 1) / threads;
        edge_score_kernel<<<blocks, threads, 0, stream>>>(src, dst, pu, pv, out, n_quads);
    }
}